// Round 3
// baseline (750.494 us; speedup 1.0000x reference)
//
#include <hip/hip_runtime.h>

#define TT 256
#define OBS 96
#define ACTD 32
#define HID 64
#define RPB 4     // batch rows per block (grid = 2048/RPB = 512 -> 2 blocks/CU)
#define XHP 200   // padded bf16 row stride: 2-way LDS bank conflict (free) on ds_read_b128
#define EPS 1e-12f

typedef __bf16 bf16x8 __attribute__((ext_vector_type(8)));
typedef float f32x4 __attribute__((ext_vector_type(4)));
typedef unsigned short u16x8 __attribute__((ext_vector_type(8)));
typedef unsigned int u32;
typedef unsigned short u16;

__device__ __forceinline__ u16 f2bf(float f) {          // fp32 -> bf16 RNE
  u32 x = __builtin_bit_cast(u32, f);
  x += 0x7fffu + ((x >> 16) & 1u);
  return (u16)(x >> 16);
}
__device__ __forceinline__ u32 pk2bf(float a, float b) {
  return (u32)f2bf(a) | ((u32)f2bf(b) << 16);
}
__device__ __forceinline__ float sigm(float x) { return 1.0f / (1.0f + __expf(-x)); }
__device__ __forceinline__ float tanh_(float x) { return 1.0f - 2.0f / (__expf(2.0f * x) + 1.0f); }

// DPP sum across each contiguous 16-lane group (all 16 lanes get the total).
// VALU-latency (~8cy/stage) instead of DS-pipe latency (~100cy/stage) of __shfl_xor.
// ctrl must be an immediate -> template parameter.
template <int CTRL>
__device__ __forceinline__ float dpp_add(float x) {
  int t = __builtin_amdgcn_update_dpp(0, __builtin_bit_cast(int, x), CTRL, 0xF, 0xF, true);
  return x + __builtin_bit_cast(float, t);
}
__device__ __forceinline__ float red16(float x) {
  x = dpp_add<0xB1>(x);   // quad_perm [1,0,3,2]  (xor 1)
  x = dpp_add<0x4E>(x);   // quad_perm [2,3,0,1]  (xor 2)
  x = dpp_add<0x124>(x);  // row_ror:4
  x = dpp_add<0x128>(x);  // row_ror:8
  return x;
}
__device__ __forceinline__ float red32(float x) {  // sum across contiguous 32 lanes
  x = red16(x);
  x += __shfl_xor(x, 16, 64);  // one DS-stage to merge the two 16-halves
  return x;
}

// One block = RPB batch rows, all 256 steps. 4 waves; wave w computes gate w
// (z cols [w*64,w*64+64)) via mfma_f32_16x16x32_bf16 (M rows RPB..15 are zeros).
// c-phase on waves 0,1 (32 lanes per row, 2 cols/lane); x-prefetch on waves 2,3.
__global__ __launch_bounds__(256, 2) void lstm_fused(
    const float* __restrict__ obss, const float* __restrict__ actions,
    const float* __restrict__ Wm, const float* __restrict__ gamma,
    const float* __restrict__ beta, const float* __restrict__ dWv,
    const float* __restrict__ dbv, float* __restrict__ out)
{
  __shared__ u16 xh[16 * XHP];          // bf16 [16 rows][192+pad]: 0..127 = x_t, 128..191 = h_t
  __shared__ float gates[4][RPB][64];   // LN'd i,j,f,o
  __shared__ float cst[RPB][64];        // c state (post-LN, fp32)

  const int tid = threadIdx.x;
  const int wv = tid >> 6;              // wave id == gate id
  const int ln = tid & 63;
  const int l15 = ln & 15;              // MFMA: A row / B col / C col
  const int quad = ln >> 4;             // MFMA: k sub-offset / C row group
  const int n0 = blockIdx.x * RPB;

  for (int i = tid; i < 16 * XHP / 2; i += 256) ((u32*)xh)[i] = 0u;  // h=0, pad rows=0
  for (int i = tid; i < RPB * 64; i += 256) ((float*)cst)[i] = 0.0f; // c=0

  // --- W as per-lane B-fragments, resident in registers (96 VGPRs) ---
  // elem j = W[k = kt*32 + quad*8 + j][col = wv*64 + nt*16 + l15]
  u16x8 bw[6][4];
  #pragma unroll
  for (int kt = 0; kt < 6; ++kt)
    #pragma unroll
    for (int nt = 0; nt < 4; ++nt)
      #pragma unroll
      for (int j = 0; j < 8; ++j)
        bw[kt][nt][j] = f2bf(Wm[(kt * 32 + quad * 8 + j) * 256 + wv * 64 + nt * 16 + l15]);

  float gg[4], gb[4];                   // this wave's gate gamma/beta per column tile
  #pragma unroll
  for (int nt = 0; nt < 4; ++nt) {
    gg[nt] = gamma[wv * 64 + nt * 16 + l15];
    gb[nt] = beta[wv * 64 + nt * 16 + l15];
  }

  // c-phase mapping (waves 0,1): row = tid>>5 (0..RPB-1), cols ec, ec+1
  const int crow = tid >> 5;
  const int ec = (tid & 31) * 2;
  const float cg0 = gamma[4 * 64 + ec], cg1 = gamma[4 * 64 + ec + 1];
  const float cb0 = beta[4 * 64 + ec],  cb1 = beta[4 * 64 + ec + 1];
  const float dw0 = dWv[ec], dw1 = dWv[ec + 1];
  const float bias = dbv[0];

  // x loaders (waves 2,3): row xr (0..RPB-1), float4 slot xq (24 obs + 8 act)
  const int lt = tid & 127;
  const int xr = lt >> 5;
  const int xq = lt & 31;
  const float* obs_p = obss + (size_t)(n0 + xr) * TT * OBS;
  const float* act_p = actions + (size_t)(n0 + xr) * TT * ACTD;

  __syncthreads();                      // zeros visible before x(0) store

  if (tid >= 128) {                     // x(0) -> LDS (bf16)
    f32x4 x0;
    if (xq < 24) x0 = *(const f32x4*)(obs_p + xq * 4);
    else         x0 = *(const f32x4*)(act_p + (xq - 24) * 4);
    u32* dst = (u32*)(xh + xr * XHP + xq * 4);
    dst[0] = pk2bf(x0[0], x0[1]);
    dst[1] = pk2bf(x0[2], x0[3]);
  }
  __syncthreads();

  for (int t = 0; t < TT; ++t) {
    // ---- waves 2,3: prefetch x(t+1) into registers (overlaps MFMA + LN) ----
    const int tn = (t < TT - 1) ? t + 1 : t;
    f32x4 xnx;
    if (tid >= 128) {
      if (xq < 24) xnx = *(const f32x4*)(obs_p + tn * OBS + xq * 4);
      else         xnx = *(const f32x4*)(act_p + tn * ACTD + (xq - 24) * 4);
    }

    // ---- A-fragments: elem j = xh[row = l15][k = kt*32 + quad*8 + j] ----
    u16x8 af[6];
    #pragma unroll
    for (int kt = 0; kt < 6; ++kt)
      af[kt] = *(const u16x8*)(xh + l15 * XHP + kt * 32 + quad * 8);

    // ---- z tile: 4 N-tiles x 6 K-tiles of mfma_f32_16x16x32_bf16 ----
    f32x4 acc[4];
    #pragma unroll
    for (int nt = 0; nt < 4; ++nt) {
      f32x4 a = {0.0f, 0.0f, 0.0f, 0.0f};
      #pragma unroll
      for (int kt = 0; kt < 6; ++kt)
        a = __builtin_amdgcn_mfma_f32_16x16x32_bf16(
            __builtin_bit_cast(bf16x8, af[kt]),
            __builtin_bit_cast(bf16x8, bw[kt][nt]), a, 0, 0, 0);
      acc[nt] = a;
    }

    // ---- per-gate LayerNorm; acc[nt][r] = z[row=quad*4+r][col=nt*16+l15] ----
    float s[4], ss[4];
    #pragma unroll
    for (int r = 0; r < 4; ++r) {
      s[r]  = acc[0][r] + acc[1][r] + acc[2][r] + acc[3][r];
      ss[r] = acc[0][r] * acc[0][r] + acc[1][r] * acc[1][r] +
              acc[2][r] * acc[2][r] + acc[3][r] * acc[3][r];
      s[r]  = red16(s[r]);              // per-row sum over 16 lanes (DPP, no DS)
      ss[r] = red16(ss[r]);
    }
    if (ln < 16) {                      // quad 0 holds valid rows 0..RPB-1
      #pragma unroll
      for (int r = 0; r < RPB; ++r) {
        const float mean = s[r] * (1.0f / 64.0f);
        const float var  = ss[r] * (1.0f / 64.0f) - mean * mean;
        const float rstd = rsqrtf(var + EPS);
        #pragma unroll
        for (int nt = 0; nt < 4; ++nt)
          gates[wv][r][nt * 16 + l15] = (acc[nt][r] - mean) * rstd * gg[nt] + gb[nt];
      }
    }
    __syncthreads();

    if (tid < 128) {
      // ---- c/h update: (row crow, cols ec, ec+1) ----
      const float2 iv = *(const float2*)&gates[0][crow][ec];
      const float2 jv = *(const float2*)&gates[1][crow][ec];
      const float2 fv = *(const float2*)&gates[2][crow][ec];
      const float2 ov = *(const float2*)&gates[3][crow][ec];
      const float2 cv = *(const float2*)&cst[crow][ec];
      const float nc0 = cv.x * sigm(fv.x + 1.0f) + sigm(iv.x) * tanh_(jv.x);
      const float nc1 = cv.y * sigm(fv.y + 1.0f) + sigm(iv.y) * tanh_(jv.y);
      float s2  = red32(nc0 + nc1);
      float ss2 = red32(nc0 * nc0 + nc1 * nc1);
      const float mean = s2 * (1.0f / 64.0f);
      const float var  = ss2 * (1.0f / 64.0f) - mean * mean;
      const float rstd = rsqrtf(var + EPS);
      const float c0 = (nc0 - mean) * rstd * cg0 + cb0;
      const float c1 = (nc1 - mean) * rstd * cg1 + cb1;
      *(float2*)&cst[crow][ec] = make_float2(c0, c1);
      const float h0 = tanh_(c0) * sigm(ov.x);
      const float h1 = tanh_(c1) * sigm(ov.y);
      *(u32*)(xh + crow * XHP + 128 + ec) = pk2bf(h0, h1);  // h(t+1) as bf16 A-input

      // ---- q[n,t] = h . dense_W + b ----
      float qp = red32(h0 * dw0 + h1 * dw1);
      if ((tid & 31) == 0) out[(size_t)(n0 + crow) * TT + t] = qp + bias;
    } else {
      // ---- commit prefetched x(t+1) (A-reads of x(t) done before barrier) ----
      u32* dst = (u32*)(xh + xr * XHP + xq * 4);
      dst[0] = pk2bf(xnx[0], xnx[1]);
      dst[1] = pk2bf(xnx[2], xnx[3]);
    }
    __syncthreads();
  }
}

extern "C" void kernel_launch(void* const* d_in, const int* in_sizes, int n_in,
                              void* d_out, int out_size, void* d_ws, size_t ws_size,
                              hipStream_t stream) {
  const float* obss    = (const float*)d_in[0];
  const float* actions = (const float*)d_in[1];
  const float* Wm      = (const float*)d_in[2];
  const float* gamma   = (const float*)d_in[3];
  const float* beta    = (const float*)d_in[4];
  const float* dWv     = (const float*)d_in[5];
  const float* dbv     = (const float*)d_in[6];
  float* out = (float*)d_out;
  lstm_fused<<<dim3(2048 / RPB), dim3(256), 0, stream>>>(obss, actions, Wm, gamma,
                                                         beta, dWv, dbv, out);
}

// Round 4
// 696.959 us; speedup vs baseline: 1.0768x; 1.0768x over previous
//
#include <hip/hip_runtime.h>

#define TT 256
#define OBS 96
#define ACTD 32
#define RPB 16     // batch rows per block; grid = 2048/16 = 128
#define XCS 136    // xchunk row stride in u16 (128 + 8 pad -> conflict-free b128)
#define HS 72      // hbuf row stride in u16 (64 + 8 pad)
#define ZS 68      // zbuf row stride in f32 (64 + 4 pad, keeps 16B align)
#define EPS 1e-12f

typedef __bf16 bf16x8 __attribute__((ext_vector_type(8)));
typedef float f32x4 __attribute__((ext_vector_type(4)));
typedef unsigned short u16x8 __attribute__((ext_vector_type(8)));
typedef unsigned int u32;
typedef unsigned short u16;

__device__ __forceinline__ u16 f2bf(float f) {          // fp32 -> bf16 RNE
  u32 x = __builtin_bit_cast(u32, f);
  x += 0x7fffu + ((x >> 16) & 1u);
  return (u16)(x >> 16);
}
__device__ __forceinline__ u32 pk2bf(float a, float b) {
  return (u32)f2bf(a) | ((u32)f2bf(b) << 16);
}
__device__ __forceinline__ float sigm(float x) { return 1.0f / (1.0f + __expf(-x)); }
__device__ __forceinline__ float tanh_(float x) { return 1.0f - 2.0f / (__expf(2.0f * x) + 1.0f); }

template <int CTRL>
__device__ __forceinline__ float dpp_add(float x) {
  int t = __builtin_amdgcn_update_dpp(0, __builtin_bit_cast(int, x), CTRL, 0xF, 0xF, true);
  return x + __builtin_bit_cast(float, t);
}
// sum over each contiguous 16-lane group, pure VALU (no DS pipe on the chain)
__device__ __forceinline__ float red16(float x) {
  x = dpp_add<0xB1>(x);   // quad_perm xor1
  x = dpp_add<0x4E>(x);   // quad_perm xor2
  x = dpp_add<0x124>(x);  // row_ror:4
  x = dpp_add<0x128>(x);  // row_ror:8
  return x;
}

// Block = 16 batch rows x 256 steps. 8 waves: wave w -> gate (w&3), N-half (w>>2),
// 12 MFMAs each (bw = 48 VGPRs -> no spill). c-phase: waves 0-3, one 16-lane group
// per batch row, 4 cols/lane -> red16-only LN. x chunk-prefetched 8 steps into regs,
// committed to LDS once per 8 steps (amortizes the vmcnt(0) barrier drain).
__global__ __launch_bounds__(512, 2) void lstm_fused(
    const float* __restrict__ obss, const float* __restrict__ actions,
    const float* __restrict__ Wm, const float* __restrict__ gamma,
    const float* __restrict__ beta, const float* __restrict__ dWv,
    const float* __restrict__ dbv, float* __restrict__ out)
{
  __shared__ u16 xchunk[8][RPB][XCS];     // bf16 x for 8 steps
  __shared__ u16 hbuf[RPB][HS];           // bf16 h(t)
  __shared__ float zbuf[4][RPB][ZS];      // raw z per gate
  __shared__ float pbuf[4][RPB][2][2];    // per-gate LN partials [half][s,ss]
  __shared__ float qbuf[RPB][8];          // q staging, flushed every 8 steps

  const int tid = threadIdx.x;
  const int wv = tid >> 6;
  const int ln = tid & 63;
  const int l15 = ln & 15;
  const int quad = ln >> 4;
  const int g = wv & 3;                   // gate
  const int half = wv >> 2;               // N-half (cols half*32 .. half*32+31)
  const int n0 = blockIdx.x * RPB;

  for (int i = tid; i < RPB * HS / 2; i += 512) ((u32*)hbuf)[i] = 0u;  // h(0)=0

  // --- W as per-lane B-fragments: elem j = W[kt*32+quad*8+j][g*64+half*32+nt*16+l15]
  u16x8 bw[6][2];
  #pragma unroll
  for (int kt = 0; kt < 6; ++kt)
    #pragma unroll
    for (int nt = 0; nt < 2; ++nt)
      #pragma unroll
      for (int j = 0; j < 8; ++j)
        bw[kt][nt][j] =
            f2bf(Wm[(kt * 32 + quad * 8 + j) * 256 + g * 64 + half * 32 + nt * 16 + l15]);

  // --- c-phase per-lane constants (waves 0-3 use them; row crow, cols c0..c0+3)
  const int crow = (wv & 3) * 4 + quad;
  const int c0 = l15 * 4;
  float ggam[4][4], gbet[4][4], cgam[4], cbet[4], dwv[4];
  #pragma unroll
  for (int e = 0; e < 4; ++e) {
    cgam[e] = gamma[4 * 64 + c0 + e];
    cbet[e] = beta[4 * 64 + c0 + e];
    dwv[e] = dWv[c0 + e];
    #pragma unroll
    for (int gg = 0; gg < 4; ++gg) {
      ggam[gg][e] = gamma[gg * 64 + c0 + e];
      gbet[gg][e] = beta[gg * 64 + c0 + e];
    }
  }
  const float bias = dbv[0];

  // --- x stager: thread -> (srow, slot); 8 float4 staged per chunk
  const int srow = tid >> 5;
  const int slot = tid & 31;              // <24: obs float4, else action float4
  const float* obs_p = obss + (size_t)(n0 + srow) * TT * OBS;
  const float* act_p = actions + (size_t)(n0 + srow) * TT * ACTD;

  f32x4 xst[8];
  #pragma unroll
  for (int s = 0; s < 8; ++s) {           // chunk 0 = steps 0..7
    int tl = s;
    xst[s] = (slot < 24) ? *(const f32x4*)(obs_p + tl * OBS + slot * 4)
                         : *(const f32x4*)(act_p + tl * ACTD + (slot - 24) * 4);
  }
  #pragma unroll
  for (int s = 0; s < 8; ++s)
    *(uint2*)&xchunk[s][srow][slot * 4] =
        make_uint2(pk2bf(xst[s][0], xst[s][1]), pk2bf(xst[s][2], xst[s][3]));

  f32x4 cst = {0.0f, 0.0f, 0.0f, 0.0f};   // c state, registers
  __syncthreads();

  for (int t = 0; t < TT; ++t) {
    const int tm = t & 7;

    if (tm == 0) {
      // issue next chunk's loads (drained once per 8 steps at the next barrier)
      #pragma unroll
      for (int s = 0; s < 8; ++s) {
        int tl = t + 8 + s; if (tl > TT - 1) tl = TT - 1;
        xst[s] = (slot < 24) ? *(const f32x4*)(obs_p + tl * OBS + slot * 4)
                             : *(const f32x4*)(act_p + tl * ACTD + (slot - 24) * 4);
      }
      if (t > 0 && wv >= 4 && wv < 6) {   // flush q for steps t-8..t-1
        const int j = tid - 256;
        const int row = j >> 3, tt = j & 7;
        out[(size_t)(n0 + row) * TT + (t - 8) + tt] = qbuf[row][tt] + bias;
      }
    }

    // ---- phase 1: A-frags + 12 MFMAs + raw z + LN partials ----
    u16x8 af[6];
    #pragma unroll
    for (int kt = 0; kt < 4; ++kt)
      af[kt] = *(const u16x8*)&xchunk[tm][l15][kt * 32 + quad * 8];
    #pragma unroll
    for (int kt = 4; kt < 6; ++kt)
      af[kt] = *(const u16x8*)&hbuf[l15][(kt - 4) * 32 + quad * 8];

    f32x4 acc0 = {0.0f, 0.0f, 0.0f, 0.0f}, acc1 = acc0;
    #pragma unroll
    for (int kt = 0; kt < 6; ++kt) {
      acc0 = __builtin_amdgcn_mfma_f32_16x16x32_bf16(
          __builtin_bit_cast(bf16x8, af[kt]), __builtin_bit_cast(bf16x8, bw[kt][0]), acc0, 0, 0, 0);
      acc1 = __builtin_amdgcn_mfma_f32_16x16x32_bf16(
          __builtin_bit_cast(bf16x8, af[kt]), __builtin_bit_cast(bf16x8, bw[kt][1]), acc1, 0, 0, 0);
    }

    float s[4], ss[4];
    #pragma unroll
    for (int r = 0; r < 4; ++r) {
      s[r]  = acc0[r] + acc1[r];
      ss[r] = acc0[r] * acc0[r] + acc1[r] * acc1[r];
      s[r]  = red16(s[r]);
      ss[r] = red16(ss[r]);
    }
    #pragma unroll
    for (int r = 0; r < 4; ++r) {         // raw z -> zbuf (normalized in phase 2)
      const int row = quad * 4 + r;
      zbuf[g][row][half * 32 + l15]      = acc0[r];
      zbuf[g][row][half * 32 + 16 + l15] = acc1[r];
    }
    if (l15 < 4) {                        // lane l15 writes row quad*4+l15 partials
      const float sv  = l15 == 0 ? s[0]  : l15 == 1 ? s[1]  : l15 == 2 ? s[2]  : s[3];
      const float ssv = l15 == 0 ? ss[0] : l15 == 1 ? ss[1] : l15 == 2 ? ss[2] : ss[3];
      *(float2*)&pbuf[g][quad * 4 + l15][half][0] = make_float2(sv, ssv);
    }
    __syncthreads();

    // ---- phase 2: waves 0-3 do gate-LN + c/h/q for row crow, cols c0..c0+3 ----
    if (wv < 4) {
      float zc[4][4];
      #pragma unroll
      for (int gg = 0; gg < 4; ++gg) {
        const f32x4 p = *(const f32x4*)&pbuf[gg][crow][0][0];   // s0,ss0,s1,ss1
        const float mean = (p[0] + p[2]) * (1.0f / 64.0f);
        const float var  = (p[1] + p[3]) * (1.0f / 64.0f) - mean * mean;
        const float rstd = rsqrtf(var + EPS);
        const f32x4 z = *(const f32x4*)&zbuf[gg][crow][c0];
        #pragma unroll
        for (int e = 0; e < 4; ++e)
          zc[gg][e] = (z[e] - mean) * rstd * ggam[gg][e] + gbet[gg][e];
      }
      float nc[4];
      #pragma unroll
      for (int e = 0; e < 4; ++e)
        nc[e] = cst[e] * sigm(zc[2][e] + 1.0f) + sigm(zc[0][e]) * tanh_(zc[1][e]);
      float s2  = red16(nc[0] + nc[1] + nc[2] + nc[3]);
      float ss2 = red16(nc[0] * nc[0] + nc[1] * nc[1] + nc[2] * nc[2] + nc[3] * nc[3]);
      const float mean = s2 * (1.0f / 64.0f);
      const float var  = ss2 * (1.0f / 64.0f) - mean * mean;
      const float rstd = rsqrtf(var + EPS);
      float h[4];
      #pragma unroll
      for (int e = 0; e < 4; ++e) {
        const float cn = (nc[e] - mean) * rstd * cgam[e] + cbet[e];
        cst[e] = cn;
        h[e] = tanh_(cn) * sigm(zc[3][e]);
      }
      *(uint2*)&hbuf[crow][c0] = make_uint2(pk2bf(h[0], h[1]), pk2bf(h[2], h[3]));
      float qp = red16(h[0] * dwv[0] + h[1] * dwv[1] + h[2] * dwv[2] + h[3] * dwv[3]);
      if (l15 == 0) qbuf[crow][tm] = qp;
    }
    if (tm == 7) {                        // commit next chunk (read starts next step)
      #pragma unroll
      for (int s = 0; s < 8; ++s)
        *(uint2*)&xchunk[s][srow][slot * 4] =
            make_uint2(pk2bf(xst[s][0], xst[s][1]), pk2bf(xst[s][2], xst[s][3]));
    }
    __syncthreads();
  }

  // final q flush (steps 248..255; last barrier made qbuf visible)
  if (wv >= 4 && wv < 6) {
    const int j = tid - 256;
    const int row = j >> 3, tt = j & 7;
    out[(size_t)(n0 + row) * TT + 248 + tt] = qbuf[row][tt] + bias;
  }
}

extern "C" void kernel_launch(void* const* d_in, const int* in_sizes, int n_in,
                              void* d_out, int out_size, void* d_ws, size_t ws_size,
                              hipStream_t stream) {
  const float* obss    = (const float*)d_in[0];
  const float* actions = (const float*)d_in[1];
  const float* Wm      = (const float*)d_in[2];
  const float* gamma   = (const float*)d_in[3];
  const float* beta    = (const float*)d_in[4];
  const float* dWv     = (const float*)d_in[5];
  const float* dbv     = (const float*)d_in[6];
  float* out = (float*)d_out;
  lstm_fused<<<dim3(2048 / RPB), dim3(512), 0, stream>>>(obss, actions, Wm, gamma,
                                                         beta, dWv, dbv, out);
}

// Round 5
// 666.366 us; speedup vs baseline: 1.1262x; 1.0459x over previous
//
#include <hip/hip_runtime.h>

#define TT 256
#define OBS 96
#define ACTD 32
#define RPB 8      // batch rows per block; grid = 256 -> 1 block/CU, all CUs busy
#define CH 8       // steps per x-chunk / z_x burst
#define XCS 136    // xchunk row stride (u16)
#define ZXS 12     // z_xT row-dim (8 valid + pad; 24B col stride: 8B-aligned, spread banks)
#define ZBS 69     // zbuf col stride (f32), odd -> spread banks
#define EPS 1e-12f

typedef _Float16 f16x8 __attribute__((ext_vector_type(8)));
typedef float f32x4 __attribute__((ext_vector_type(4)));
typedef unsigned short u16x8 __attribute__((ext_vector_type(8)));
typedef unsigned int u32;
typedef unsigned short u16;

__device__ __forceinline__ u16 f2h(float f) {            // fp32 -> fp16 RNE
  return __builtin_bit_cast(u16, (_Float16)f);
}
__device__ __forceinline__ u32 pk2h(float a, float b) {
  return (u32)f2h(a) | ((u32)f2h(b) << 16);
}
__device__ __forceinline__ float h2f_lo(u32 v) {
  return (float)__builtin_bit_cast(_Float16, (u16)(v & 0xffffu));
}
__device__ __forceinline__ float h2f_hi(u32 v) {
  return (float)__builtin_bit_cast(_Float16, (u16)(v >> 16));
}
__device__ __forceinline__ float sigm(float x) { return 1.0f / (1.0f + __expf(-x)); }
__device__ __forceinline__ float tanh_(float x) { return 1.0f - 2.0f / (__expf(2.0f * x) + 1.0f); }

template <int CTRL>
__device__ __forceinline__ float dpp_add(float x) {
  int t = __builtin_amdgcn_update_dpp(0, __builtin_bit_cast(int, x), CTRL, 0xF, 0xF, true);
  return x + __builtin_bit_cast(float, t);
}
__device__ __forceinline__ float red16(float x) {   // sum within 16-lane groups, pure VALU
  x = dpp_add<0xB1>(x);   // quad_perm xor1
  x = dpp_add<0x4E>(x);   // quad_perm xor2
  x = dpp_add<0x124>(x);  // row_ror:4
  x = dpp_add<0x128>(x);  // row_ror:8
  return x;
}
__device__ __forceinline__ float red64(float x) {   // full-wave sum
  x = red16(x);
  x += __shfl_xor(x, 16, 64);
  x += __shfl_xor(x, 32, 64);
  return x;
}

// Block = 8 batch rows x 256 steps, 8 waves. Wave w owns z cols
// [g*64+half*32, +32), g=w&3, half=w>>2. Per-step chain: h-only MFMA (K=64,
// 2-deep) + precomputed z_x (fp16 LDS) + DPP LN partials | barrier | LN + gate
// math at 1 element/lane over all 8 waves (row=wave, col=lane) | barrier.
// z_x = x.Wx burst-computed once per 8 steps (off the recurrence chain).
__global__ __launch_bounds__(512, 2) void lstm_fused(
    const float* __restrict__ obss, const float* __restrict__ actions,
    const float* __restrict__ Wm, const float* __restrict__ gamma,
    const float* __restrict__ beta, const float* __restrict__ dWv,
    const float* __restrict__ dbv, float* __restrict__ out)
{
  __shared__ u16 xchunk[CH][RPB][XCS];     // fp16 x, 8 steps
  __shared__ u16 zxT[CH][256][ZXS];        // fp16 z_x, transposed [col][row]
  __shared__ float zbuf[4][16][ZBS];       // full z per gate (rows 8-15 garbage)
  __shared__ float pbuf[4][16][4];         // gate-LN partials: s0,ss0,s1,ss1
  __shared__ u16 hbuf[RPB][72];            // fp16 h(t)
  __shared__ float qbuf[CH][RPB];          // q staging

  const int tid = threadIdx.x;
  const int wv = tid >> 6;
  const int ln = tid & 63;
  const int l15 = ln & 15;
  const int quad = ln >> 4;
  const int g = wv & 3;
  const int half = wv >> 2;
  const int n0 = blockIdx.x * RPB;
  const int c0 = g * 64 + half * 32 + l15;  // this lane's z col (nt=0); nt=1 -> c0+16

  for (int i = tid; i < RPB * 72 / 2; i += 512) ((u32*)hbuf)[i] = 0u;  // h(0)=0

  // W B-fragments (fp16): elem j = W[kt*32+quad*8+j][c0 + nt*16]
  u16x8 bw[6][2];
  #pragma unroll
  for (int kt = 0; kt < 6; ++kt)
    #pragma unroll
    for (int nt = 0; nt < 2; ++nt)
      #pragma unroll
      for (int j = 0; j < 8; ++j)
        bw[kt][nt][j] = f2h(Wm[(kt * 32 + quad * 8 + j) * 256 + c0 + nt * 16]);

  // phase-2 per-lane constants (row = wv, col = ln)
  float ggam[4], gbet[4];
  #pragma unroll
  for (int gg = 0; gg < 4; ++gg) {
    ggam[gg] = gamma[gg * 64 + ln];
    gbet[gg] = beta[gg * 64 + ln];
  }
  const float cgam = gamma[4 * 64 + ln], cbet = beta[4 * 64 + ln];
  const float dw = dWv[ln];
  const float bias = dbv[0];

  // x stager: thread -> (srow, slot), slices sp, sp+2, sp+4, sp+6
  const int sp = tid >> 8;
  const int srow = (tid >> 5) & 7;
  const int slot = tid & 31;               // <24: obs float4, else action float4
  const float* obs_p = obss + (size_t)(n0 + srow) * TT * OBS;
  const float* act_p = actions + (size_t)(n0 + srow) * TT * ACTD;

  f32x4 xst[4];
  #pragma unroll
  for (int k = 0; k < 4; ++k) {            // chunk 0 = steps 0..7
    const int s = sp + 2 * k;
    xst[k] = (slot < 24) ? *(const f32x4*)(obs_p + s * OBS + slot * 4)
                         : *(const f32x4*)(act_p + s * ACTD + (slot - 24) * 4);
  }
  #pragma unroll
  for (int k = 0; k < 4; ++k) {
    const int s = sp + 2 * k;
    *(uint2*)&xchunk[s][srow][slot * 4] =
        make_uint2(pk2h(xst[k][0], xst[k][1]), pk2h(xst[k][2], xst[k][3]));
  }

  float creg = 0.0f;                       // c[row=wv][col=ln]
  __syncthreads();

  for (int t = 0; t < TT; ++t) {
    const int tm = t & 7;

    if (tm == 0) {
      if (t > 0 && tid < 64) {             // flush q for steps t-8..t-1
        const int s = tid >> 3, row = tid & 7;
        out[(size_t)(n0 + row) * TT + (t - 8) + s] = qbuf[s][row] + bias;
      }
      #pragma unroll
      for (int k = 0; k < 4; ++k) {        // prefetch next chunk into regs
        int tl = t + 8 + sp + 2 * k; if (tl > TT - 1) tl = TT - 1;
        xst[k] = (slot < 24) ? *(const f32x4*)(obs_p + tl * OBS + slot * 4)
                             : *(const f32x4*)(act_p + tl * ACTD + (slot - 24) * 4);
      }
      // z_x burst for this chunk: wave computes its 2 col-tiles for 8 slices
      #pragma unroll
      for (int s = 0; s < CH; ++s) {
        u16x8 afx[4];
        #pragma unroll
        for (int kt = 0; kt < 4; ++kt)
          afx[kt] = *(const u16x8*)&xchunk[s][l15 & 7][kt * 32 + quad * 8];
        f32x4 ax0 = {0.f, 0.f, 0.f, 0.f}, ax1 = ax0;
        #pragma unroll
        for (int kt = 0; kt < 4; ++kt) {
          ax0 = __builtin_amdgcn_mfma_f32_16x16x32_f16(
              __builtin_bit_cast(f16x8, afx[kt]), __builtin_bit_cast(f16x8, bw[kt][0]), ax0, 0, 0, 0);
          ax1 = __builtin_amdgcn_mfma_f32_16x16x32_f16(
              __builtin_bit_cast(f16x8, afx[kt]), __builtin_bit_cast(f16x8, bw[kt][1]), ax1, 0, 0, 0);
        }
        if (quad < 2) {                    // valid C rows 0..7 (quad 0,1)
          *(uint2*)&zxT[s][c0][quad * 4] =
              make_uint2(pk2h(ax0[0], ax0[1]), pk2h(ax0[2], ax0[3]));
          *(uint2*)&zxT[s][c0 + 16][quad * 4] =
              make_uint2(pk2h(ax1[0], ax1[1]), pk2h(ax1[2], ax1[3]));
        }
      }
    }

    // ---- phase 1: z = h.Wh (2-deep MFMA) + z_x ----
    const u16x8 afh0 = *(const u16x8*)&hbuf[l15 & 7][quad * 8];
    const u16x8 afh1 = *(const u16x8*)&hbuf[l15 & 7][32 + quad * 8];
    f32x4 acc0 = {0.f, 0.f, 0.f, 0.f}, acc1 = acc0;
    acc0 = __builtin_amdgcn_mfma_f32_16x16x32_f16(
        __builtin_bit_cast(f16x8, afh0), __builtin_bit_cast(f16x8, bw[4][0]), acc0, 0, 0, 0);
    acc1 = __builtin_amdgcn_mfma_f32_16x16x32_f16(
        __builtin_bit_cast(f16x8, afh0), __builtin_bit_cast(f16x8, bw[4][1]), acc1, 0, 0, 0);
    acc0 = __builtin_amdgcn_mfma_f32_16x16x32_f16(
        __builtin_bit_cast(f16x8, afh1), __builtin_bit_cast(f16x8, bw[5][0]), acc0, 0, 0, 0);
    acc1 = __builtin_amdgcn_mfma_f32_16x16x32_f16(
        __builtin_bit_cast(f16x8, afh1), __builtin_bit_cast(f16x8, bw[5][1]), acc1, 0, 0, 0);

    {
      const uint2 zx0 = *(const uint2*)&zxT[tm][c0][(quad & 1) * 4];
      const uint2 zx1 = *(const uint2*)&zxT[tm][c0 + 16][(quad & 1) * 4];
      acc0[0] += h2f_lo(zx0.x); acc0[1] += h2f_hi(zx0.x);
      acc0[2] += h2f_lo(zx0.y); acc0[3] += h2f_hi(zx0.y);
      acc1[0] += h2f_lo(zx1.x); acc1[1] += h2f_hi(zx1.x);
      acc1[2] += h2f_lo(zx1.y); acc1[3] += h2f_hi(zx1.y);
    }

    float s[4], ss[4];
    #pragma unroll
    for (int r = 0; r < 4; ++r) {
      s[r]  = red16(acc0[r] + acc1[r]);
      ss[r] = red16(acc0[r] * acc0[r] + acc1[r] * acc1[r]);
    }
    #pragma unroll
    for (int r = 0; r < 4; ++r) {
      zbuf[g][quad * 4 + r][half * 32 + l15]      = acc0[r];
      zbuf[g][quad * 4 + r][half * 32 + 16 + l15] = acc1[r];
    }
    if (l15 < 4) {
      const float sv  = l15 == 0 ? s[0]  : l15 == 1 ? s[1]  : l15 == 2 ? s[2]  : s[3];
      const float ssv = l15 == 0 ? ss[0] : l15 == 1 ? ss[1] : l15 == 2 ? ss[2] : ss[3];
      *(float2*)&pbuf[g][quad * 4 + l15][half * 2] = make_float2(sv, ssv);
    }
    __syncthreads();

    // ---- phase 2: row = wv, col = ln (1 element/lane, all 8 waves) ----
    float zc[4];
    #pragma unroll
    for (int gg = 0; gg < 4; ++gg) {
      const f32x4 p = *(const f32x4*)&pbuf[gg][wv][0];   // s0,ss0,s1,ss1 (broadcast)
      const float mean = (p[0] + p[2]) * (1.0f / 64.0f);
      const float var  = (p[1] + p[3]) * (1.0f / 64.0f) - mean * mean;
      const float rstd = rsqrtf(var + EPS);
      zc[gg] = (zbuf[gg][wv][ln] - mean) * rstd * ggam[gg] + gbet[gg];
    }
    const float nc = creg * sigm(zc[2] + 1.0f) + sigm(zc[0]) * tanh_(zc[1]);
    const float s2  = red64(nc);
    const float ss2 = red64(nc * nc);
    const float mean = s2 * (1.0f / 64.0f);
    const float var  = ss2 * (1.0f / 64.0f) - mean * mean;
    const float rstd = rsqrtf(var + EPS);
    const float cn = (nc - mean) * rstd * cgam + cbet;
    creg = cn;
    const float h = tanh_(cn) * sigm(zc[3]);
    hbuf[wv][ln] = f2h(h);                                // next step's A-input
    const float qp = red64(h * dw);
    if (ln == 0) qbuf[tm][wv] = qp;

    if (tm == 7) {                          // commit prefetched chunk
      #pragma unroll
      for (int k = 0; k < 4; ++k) {
        const int scm = sp + 2 * k;
        *(uint2*)&xchunk[scm][srow][slot * 4] =
            make_uint2(pk2h(xst[k][0], xst[k][1]), pk2h(xst[k][2], xst[k][3]));
      }
    }
    __syncthreads();
  }

  if (tid < 64) {                           // final q flush (steps 248..255)
    const int s = tid >> 3, row = tid & 7;
    out[(size_t)(n0 + row) * TT + 248 + s] = qbuf[s][row] + bias;
  }
}

extern "C" void kernel_launch(void* const* d_in, const int* in_sizes, int n_in,
                              void* d_out, int out_size, void* d_ws, size_t ws_size,
                              hipStream_t stream) {
  const float* obss    = (const float*)d_in[0];
  const float* actions = (const float*)d_in[1];
  const float* Wm      = (const float*)d_in[2];
  const float* gamma   = (const float*)d_in[3];
  const float* beta    = (const float*)d_in[4];
  const float* dWv     = (const float*)d_in[5];
  const float* dbv     = (const float*)d_in[6];
  float* out = (float*)d_out;
  lstm_fused<<<dim3(2048 / RPB), dim3(512), 0, stream>>>(obss, actions, Wm, gamma,
                                                         beta, dWv, dbv, out);
}